// Round 5
// baseline (595.465 us; speedup 1.0000x reference)
//
#include <hip/hip_runtime.h>
#include <hip/hip_bf16.h>
#include <stdint.h>

#define NN   100000
#define NE   1600000
#define KIN  256
#define FOUT 128
#define CH   13      // chunks of 8192 nodes (col >> 13), 2 MB of h per chunk
#define CHB  13
#define RPW  16      // rows per wave in spmm

typedef __attribute__((ext_vector_type(8))) short short8;
typedef __attribute__((ext_vector_type(4))) float f32x4;
typedef __attribute__((ext_vector_type(2))) float f32x2;

static __device__ __forceinline__ unsigned short f2bf(float f) {
  unsigned int u = __float_as_uint(f);
  u += 0x7fffu + ((u >> 16) & 1u);   // RNE (inputs finite)
  return (unsigned short)(u >> 16);
}

static __device__ __forceinline__ short8 pack8(float4 u, float4 v) {
  short8 r;
  r[0] = (short)f2bf(u.x); r[1] = (short)f2bf(u.y);
  r[2] = (short)f2bf(u.z); r[3] = (short)f2bf(u.w);
  r[4] = (short)f2bf(v.x); r[5] = (short)f2bf(v.y);
  r[6] = (short)f2bf(v.z); r[7] = (short)f2bf(v.w);
  return r;
}

// ---------------------------------------------------------------------------
// 1) Fused setup: blocks [0,6250) build row_ptr (linear edge scan);
//    blocks [6250,6378) transpose-convert W -> wt[which][n][k] bf16.
__global__ __launch_bounds__(256) void setup(const int* __restrict__ rows0,
                                             const int* __restrict__ rows1,
                                             const float* __restrict__ W0,
                                             const float* __restrict__ W1,
                                             int* __restrict__ rp0,
                                             int* __restrict__ rp1,
                                             unsigned short* __restrict__ wt) {
  const int which = blockIdx.y;
  const int bx = blockIdx.x;
  if (bx < 6250) {
    const int e = bx * 256 + threadIdx.x;              // 6250*256 == NE
    const int* rows = which ? rows1 : rows0;
    int* rp = which ? rp1 : rp0;
    int r1 = rows[e];
    int r2 = (e + 1 < NE) ? rows[e + 1] : NN;
    if (e == 0)
      for (int r = 0; r <= r1; ++r) rp[r] = 0;
    for (int r = r1 + 1; r <= r2; ++r) rp[r] = e + 1;
  } else {
    const int n = bx - 6250;                           // 0..127
    const int k = threadIdx.x;                         // 0..255
    const float* W = which ? W1 : W0;
    wt[(size_t)which * (FOUT * KIN) + n * KIN + k] = f2bf(W[k * FOUT + n]);
  }
}

// ---------------------------------------------------------------------------
// 2) Bucket edges per row by chunk-of-col (13-way ballot counting sort) and
//    pack (val 15b fixed-point | col 17b) -> uint32. Emits chunk-run starts
//    ofs[c*NN + r] (c=0..12) and end sentinel ofs[13*NN + r] = rp[r+1].
//    Runs are ANY partition of the row's edges -> correctness never depends
//    on the bucketing; locality does. len>64 fallback: one run in slot 0.
__global__ __launch_bounds__(256) void bucket_edges(
    const int* __restrict__ rp0, const int* __restrict__ cols0, const float* __restrict__ vals0,
    const int* __restrict__ rp1, const int* __restrict__ cols1, const float* __restrict__ vals1,
    unsigned* __restrict__ eb0, unsigned* __restrict__ eb1,
    int* __restrict__ ofs0, int* __restrict__ ofs1) {
  const int r    = blockIdx.x * 4 + (threadIdx.x >> 6);   // 25000*4 == NN
  const int lane = threadIdx.x & 63;
  const int*   rp;  const int* cols; const float* vals;
  unsigned*    eb;  int* ofs;
  if (blockIdx.y) { rp = rp1; cols = cols1; vals = vals1; eb = eb1; ofs = ofs1; }
  else            { rp = rp0; cols = cols0; vals = vals0; eb = eb0; ofs = ofs0; }

  const int s = rp[r], e = rp[r + 1];
  const int len = e - s;

  if (len <= 64) {
    const bool have = lane < len;
    int c = 0; float v = 0.f;
    if (have) { c = cols[s + lane]; v = vals[s + lane]; }
    const int key = c >> CHB;                     // 0..12
    const unsigned q = (unsigned)(v * 32767.f + 0.5f);
    const unsigned pe = (q << 17) | (unsigned)c;

    unsigned long long bal[CH];
    int cnt[CH];
#pragma unroll
    for (int k = 0; k < CH; ++k) {
      bal[k] = __ballot(have && (key == k));
      cnt[k] = __popcll(bal[k]);
    }
    // prefix sums without dynamic register indexing (cndmask chains)
    int pl_key = 0, pl_lane = 0;
    unsigned long long mybal = 0;
#pragma unroll
    for (int k = 0; k < CH; ++k) {
      pl_key  += (k < key)  ? cnt[k] : 0;
      pl_lane += (k < lane) ? cnt[k] : 0;
      mybal    = (k == key) ? bal[k] : mybal;
    }
    if (have) {
      const unsigned long long lt = (lane == 0) ? 0ULL : ((~0ULL) >> (64 - lane));
      const int rank = pl_key + __popcll(mybal & lt);
      eb[s + rank] = pe;
    }
    if (lane < CH)        ofs[lane * NN + r] = s + pl_lane;
    else if (lane == CH)  ofs[CH * NN + r]   = e;
  } else {
    for (int j = lane; j < len; j += 64) {
      const unsigned q = (unsigned)(vals[s + j] * 32767.f + 0.5f);
      eb[s + j] = (q << 17) | (unsigned)cols[s + j];
    }
    if (lane == 0)        ofs[r] = s;             // run 0 = whole row
    else if (lane <= CH)  ofs[lane * NN + r] = e; // runs 1..12 empty + sentinel
  }
}

// ---------------------------------------------------------------------------
// 3) GEMM, single pass over x (unchanged from R4): block = 32 rows, 4 waves =
//    {which} x {64-col half}; wave tile 32x64; LDS-staged coalesced epilogue.
__global__ __launch_bounds__(256) void gemm_mfma(const float* __restrict__ x,
                                                 const unsigned short* __restrict__ wt,
                                                 unsigned short* __restrict__ h) {
  __shared__ __align__(16) unsigned short tile[4][32 * 64];   // 16 KB

  const int tid  = threadIdx.x;
  const int lane = tid & 63;
  const int wv   = tid >> 6;
  const int which = wv >> 1;
  const int colbase = (wv & 1) * 64;
  const int rowbase = blockIdx.x * 32;
  const int m    = lane & 15;
  const int quad = lane >> 4;

  const unsigned short* w = wt + (size_t)which * (FOUT * KIN);
  unsigned short* hh = h + (size_t)which * NN * FOUT;

  const float* ap0 = x + (size_t)(rowbase + m) * KIN + quad * 8;
  const float* ap1 = x + (size_t)(rowbase + 16 + m) * KIN + quad * 8;
  const unsigned short* b0p = w + (size_t)(colbase + 0  + m) * KIN + quad * 8;
  const unsigned short* b1p = w + (size_t)(colbase + 16 + m) * KIN + quad * 8;
  const unsigned short* b2p = w + (size_t)(colbase + 32 + m) * KIN + quad * 8;
  const unsigned short* b3p = w + (size_t)(colbase + 48 + m) * KIN + quad * 8;

  f32x4 acc[2][4];
#pragma unroll
  for (int i = 0; i < 2; ++i)
#pragma unroll
    for (int j = 0; j < 4; ++j)
      acc[i][j] = (f32x4){0.f, 0.f, 0.f, 0.f};

#pragma unroll 2
  for (int ko = 0; ko < KIN; ko += 32) {
    float4 a0lo = *(const float4*)(ap0 + ko);
    float4 a0hi = *(const float4*)(ap0 + ko + 4);
    float4 a1lo = *(const float4*)(ap1 + ko);
    float4 a1hi = *(const float4*)(ap1 + ko + 4);
    short8 b0 = *(const short8*)(b0p + ko);
    short8 b1 = *(const short8*)(b1p + ko);
    short8 b2 = *(const short8*)(b2p + ko);
    short8 b3 = *(const short8*)(b3p + ko);
    short8 a0 = pack8(a0lo, a0hi);
    short8 a1 = pack8(a1lo, a1hi);
    acc[0][0] = __builtin_amdgcn_mfma_f32_16x16x32_bf16(a0, b0, acc[0][0], 0, 0, 0);
    acc[0][1] = __builtin_amdgcn_mfma_f32_16x16x32_bf16(a0, b1, acc[0][1], 0, 0, 0);
    acc[0][2] = __builtin_amdgcn_mfma_f32_16x16x32_bf16(a0, b2, acc[0][2], 0, 0, 0);
    acc[0][3] = __builtin_amdgcn_mfma_f32_16x16x32_bf16(a0, b3, acc[0][3], 0, 0, 0);
    acc[1][0] = __builtin_amdgcn_mfma_f32_16x16x32_bf16(a1, b0, acc[1][0], 0, 0, 0);
    acc[1][1] = __builtin_amdgcn_mfma_f32_16x16x32_bf16(a1, b1, acc[1][1], 0, 0, 0);
    acc[1][2] = __builtin_amdgcn_mfma_f32_16x16x32_bf16(a1, b2, acc[1][2], 0, 0, 0);
    acc[1][3] = __builtin_amdgcn_mfma_f32_16x16x32_bf16(a1, b3, acc[1][3], 0, 0, 0);
  }

  // D layout: col = lane&15 (=m), row = quad*4 + reg  [m89/m91 verified]
#pragma unroll
  for (int i = 0; i < 2; ++i)
#pragma unroll
    for (int reg = 0; reg < 4; ++reg)
#pragma unroll
      for (int j = 0; j < 4; ++j)
        tile[wv][(i * 16 + quad * 4 + reg) * 64 + j * 16 + m] = f2bf(acc[i][j][reg]);

#pragma unroll
  for (int p = 0; p < 4; ++p) {
    int row = p * 8 + (lane >> 3);
    int colb = (lane & 7) * 8;
    uint4 v = *(const uint4*)&tile[wv][row * 64 + colb];
    *(uint4*)&hh[(size_t)(rowbase + row) * FOUT + colbase + colb] = v;
  }
}

// ---------------------------------------------------------------------------
// 4) Chunk-phase SpMM + relu. 1563 blocks (all co-resident at 4 waves/block)
//    -> loose lock-step through matrix x chunk phases; during a phase nearly
//    all gathers target one 2 MB h-slice (L2-resident per XCD).
//    Wave owns RPW=16 rows; fp32 accumulators in registers (compile-time
//    indexed); edge words are scalar (s_load), gathers 256B coalesced.
__global__ __launch_bounds__(256) void spmm_chunked(
    const unsigned* __restrict__ eb0, const unsigned* __restrict__ eb1,
    const int* __restrict__ ofs0, const int* __restrict__ ofs1,
    const unsigned short* __restrict__ h, float* __restrict__ out) {
  const int lane = threadIdx.x & 63;
  const int wid  = blockIdx.x * 4 + (threadIdx.x >> 6);
  const int r0   = wid * RPW;                     // 1563*4*16 = 100032 >= NN
  const int fo   = lane * 2;

  float ax[RPW], ay[RPW];
#pragma unroll
  for (int i = 0; i < RPW; ++i) { ax[i] = 0.f; ay[i] = 0.f; }

#pragma unroll
  for (int mm = 0; mm < 2; ++mm) {
    const unsigned* eb = mm ? eb1 : eb0;
    const int* ofs = mm ? ofs1 : ofs0;
    const unsigned short* hs = h + (size_t)mm * NN * FOUT;
    for (int c = 0; c < CH; ++c) {
      int va = 0, vb = 0;
      if (lane < RPW && r0 + lane < NN) {
        va = ofs[c * NN + r0 + lane];
        vb = ofs[(c + 1) * NN + r0 + lane];
      }
#pragma unroll
      for (int i = 0; i < RPW; ++i) {
        if (r0 + i < NN) {
          int a = __builtin_amdgcn_readlane(va, i);
          int b = __builtin_amdgcn_readlane(vb, i);
          for (int j = a; j < b; ++j) {
            unsigned pe = eb[j];                  // uniform -> scalar load
            int col = pe & 0x1FFFF;
            float v = (float)(pe >> 17) * (1.f / 32767.f);
            unsigned g = *(const unsigned*)(hs + (size_t)col * FOUT + fo);
            ax[i] += v * __uint_as_float(g << 16);
            ay[i] += v * __uint_as_float(g & 0xffff0000u);
          }
        }
      }
    }
  }

#pragma unroll
  for (int i = 0; i < RPW; ++i) {
    int r = r0 + i;
    if (r < NN) {
      f32x2 o;
      o.x = ax[i] > 0.f ? ax[i] : 0.f;
      o.y = ay[i] > 0.f ? ay[i] : 0.f;
      __builtin_nontemporal_store(o, (f32x2*)(out + (size_t)r * FOUT + fo));
    }
  }
}

// ---------------------------------------------------------------------------
extern "C" void kernel_launch(void* const* d_in, const int* in_sizes, int n_in,
                              void* d_out, int out_size, void* d_ws, size_t ws_size,
                              hipStream_t stream) {
  const float* x     = (const float*)d_in[0];
  const int*   rows0 = (const int*)d_in[1];
  const int*   cols0 = (const int*)d_in[2];
  const float* vals0 = (const float*)d_in[3];
  const int*   rows1 = (const int*)d_in[4];
  const int*   cols1 = (const int*)d_in[5];
  const float* vals1 = (const float*)d_in[6];
  const float* W0    = (const float*)d_in[7];
  const float* W1    = (const float*)d_in[8];
  float* out = (float*)d_out;

  // ws layout (16B aligned):
  //   wt   : 131,072 B                 @ 0
  //   h    : 51,200,000 B              @ 131,072
  //   rp0  : (NN+1) i32 (pad 400,064)  @ 51,331,072
  //   rp1  :                           @ 51,731,136  (ends 52,131,200 -> pad)
  //   eb0  : NE u32 = 6,400,000 B      @ 52,131,328
  //   eb1  :                           @ 58,531,328
  //   ofs0 : 14*NN i32 = 5,600,000 B   @ 64,931,328
  //   ofs1 :                           @ 70,531,328  (ends 76,131,328)
  char* ws = (char*)d_ws;
  unsigned short* wt = (unsigned short*)(ws);
  unsigned short* h  = (unsigned short*)(ws + 131072);
  int* rp0 = (int*)(ws + 51331072);
  int* rp1 = (int*)(ws + 51731136);
  unsigned* eb0 = (unsigned*)(ws + 52131328);
  unsigned* eb1 = (unsigned*)(ws + 58531328);
  int* ofs0 = (int*)(ws + 64931328);
  int* ofs1 = (int*)(ws + 70531328);

  setup<<<dim3(6378, 2), 256, 0, stream>>>(rows0, rows1, W0, W1, rp0, rp1, wt);
  bucket_edges<<<dim3(NN / 4, 2), 256, 0, stream>>>(rp0, cols0, vals0,
                                                    rp1, cols1, vals1,
                                                    eb0, eb1, ofs0, ofs1);
  gemm_mfma<<<NN / 32, 256, 0, stream>>>(x, wt, h);
  spmm_chunked<<<(NN + 4 * RPW - 1) / (4 * RPW), 256, 0, stream>>>(
      eb0, eb1, ofs0, ofs1, h, out);
}